// Round 5
// baseline (312.339 us; speedup 1.0000x reference)
//
#include <hip/hip_runtime.h>
#include <stdint.h>

#define TWO_PI_F 6.28318530717958647692f
#define EPSF 1e-6f
#define DTF 0.01f
#define KCOUP 2.0f

// ---- GEMM geometry ----
#define BM 128
#define BN 96
#define BK 64
#define KITERS 32                 // 2048 / 64
#define NTILES 7                  // 672 / 96, exact
#define GTHREADS 256
#define B_TILE_BYTES (BN * 128)   // 12288
#define A_TILE_BYTES (BM * 128)   // 16384
#define BUF_BYTES (B_TILE_BYTES + A_TILE_BYTES)   // 28672 per pipeline buffer
#define WCHUNK (672 * 128)        // 86016 bytes per K-chunk of B image
#define W_IMG_BYTES ((size_t)KITERS * WCHUNK)          // 2,752,512
#define XB_BYTES ((size_t)32768 * 2048 * 2)            // 134,217,728
#define WS_NEED_FULL (W_IMG_BYTES + XB_BYTES)
#define WS_NEED_MIN  W_IMG_BYTES

typedef __attribute__((ext_vector_type(8)))  __bf16         bf16x8;
typedef __attribute__((ext_vector_type(8)))  unsigned short ushort8v;
typedef __attribute__((ext_vector_type(16))) float          f32x16;

__device__ __forceinline__ unsigned short f2bf(float f) {
  unsigned u = __builtin_bit_cast(unsigned, f);
  u = (u + 0x7FFFu + ((u >> 16) & 1u)) >> 16;   // RNE
  return (unsigned short)u;
}

// ---------- prep_w: W (f32) -> swizzled bf16 image [t][col][slot*16B] ----------
__global__ void prep_w(const float* __restrict__ Wd, const float* __restrict__ Wt,
                       const float* __restrict__ Wg, char* __restrict__ wbB) {
  int id = blockIdx.x * 256 + threadIdx.x;      // 672 * 64 total
  if (id >= 672 * 64) return;
  int col = id >> 6;
  int rem = id & 63, t = rem >> 1, h = rem & 1;
  const float* src = (col < 32)  ? Wd + (size_t)col * 2048
                   : (col < 160) ? Wt + (size_t)(col - 32) * 2048
                                 : Wg + (size_t)(col - 160) * 2048;
  src += t * 64 + h * 32;
  char* dst = wbB + ((size_t)t * 672 + col) * 128;
  #pragma unroll
  for (int s4 = 0; s4 < 4; s4++) {
    float4 a = ((const float4*)src)[s4 * 2];
    float4 b = ((const float4*)src)[s4 * 2 + 1];
    ushort8v v;
    v[0] = f2bf(a.x); v[1] = f2bf(a.y); v[2] = f2bf(a.z); v[3] = f2bf(a.w);
    v[4] = f2bf(b.x); v[5] = f2bf(b.y); v[6] = f2bf(b.z); v[7] = f2bf(b.w);
    int slot = (h * 4 + s4) ^ (col & 7);
    *(ushort8v*)(dst + slot * 16) = v;
  }
}

// ---------- prep_x: x f32 -> plain row-major bf16 (L3-resident 134 MB) ----------
__global__ void prep_x(const float* __restrict__ x, unsigned short* __restrict__ xb,
                       int n8) {
  int i = blockIdx.x * 256 + threadIdx.x;       // one thread per 8 elems
  if (i >= n8) return;
  const float4* s = (const float4*)x + (size_t)i * 2;
  float4 a = s[0], b = s[1];
  ushort8v v;
  v[0] = f2bf(a.x); v[1] = f2bf(a.y); v[2] = f2bf(a.z); v[3] = f2bf(a.w);
  v[4] = f2bf(b.x); v[5] = f2bf(b.y); v[6] = f2bf(b.z); v[7] = f2bf(b.w);
  *(ushort8v*)(xb + (size_t)i * 8) = v;
}

// ---------- K1 (fast path): double-buffered LDS + counted vmcnt pipeline ----------
__launch_bounds__(GTHREADS, 2)
__global__ void gemm(const unsigned short* __restrict__ xb,
                     const char* __restrict__ wbB, float* __restrict__ z) {
  __shared__ __align__(16) char smem[2 * BUF_BYTES];

  const int tid = threadIdx.x;
  const int wid = tid >> 6, lane = tid & 63;

  // XCD-aware: each XCD owns 32 exclusive row panels; 7 n-tiles of a panel adjacent
  const int bid = blockIdx.x;
  const int xcd = bid & 7, j = bid >> 3;
  const int panel = xcd * 32 + j / 7;
  const int n = j % 7;
  const size_t row0 = (size_t)panel * BM;

  f32x16 acc[3];
  #pragma unroll
  for (int f = 0; f < 3; f++)
    #pragma unroll
    for (int jj = 0; jj < 16; jj++) acc[f][jj] = 0.f;

  // A gll source: thread stages 16B; dest row = rnd*32 + (tid>>3), slot = tid&7
  const int arow_s = tid >> 3;
  const int aslot  = (tid & 7) ^ (arow_s & 7);
  const unsigned short* asrc0 = xb + (row0 + arow_s) * 2048 + aslot * 8;
  const char* bsrc0 = wbB + n * B_TILE_BYTES;

  // frag read bases
  const int arf = wid * 32 + (lane & 31);
  const int arf7 = arf & 7;

#define STAGE(buf, t)                                                        \
  {                                                                          \
    char* Bs_ = smem + (buf) * BUF_BYTES;                                    \
    char* As_ = Bs_ + B_TILE_BYTES;                                          \
    const char* bsrc = bsrc0 + (size_t)(t) * WCHUNK;                         \
    _Pragma("unroll")                                                        \
    for (int rnd = 0; rnd < 3; rnd++) {                                      \
      int off = rnd * 4096 + tid * 16;                                       \
      __builtin_amdgcn_global_load_lds(                                      \
          (const __attribute__((address_space(1))) void*)(bsrc + off),       \
          (__attribute__((address_space(3))) void*)(Bs_ + off), 16, 0, 0);   \
    }                                                                        \
    const unsigned short* asrc = asrc0 + (t) * 64;                           \
    _Pragma("unroll")                                                        \
    for (int rnd = 0; rnd < 4; rnd++) {                                      \
      __builtin_amdgcn_global_load_lds(                                      \
          (const __attribute__((address_space(1))) void*)(asrc + (size_t)rnd * 32 * 2048), \
          (__attribute__((address_space(3))) void*)(As_ + rnd * 4096 + tid * 16), 16, 0, 0); \
    }                                                                        \
  }

  STAGE(0, 0);                                   // 7 loads in flight (tile 0)
  for (int t = 0; t < KITERS; t++) {
    const int cur = t & 1;
    if (t + 1 < KITERS) {
      STAGE(cur ^ 1, t + 1);                     // +7 -> 14 outstanding
      asm volatile("s_waitcnt vmcnt(7)" ::: "memory");   // oldest 7 (tile t) landed
    } else {
      asm volatile("s_waitcnt vmcnt(0)" ::: "memory");
    }
    __builtin_amdgcn_s_barrier();                // all waves: tile t visible

    const char* Bs = smem + cur * BUF_BYTES;
    const char* afbase = Bs + B_TILE_BYTES + arf * 128;
    #pragma unroll
    for (int k16 = 0; k16 < 4; k16++) {
      int sl = k16 * 2 + (lane >> 5);
      bf16x8 af = __builtin_bit_cast(bf16x8,
          *(const ushort8v*)(afbase + ((sl ^ arf7) << 4)));
      #pragma unroll
      for (int fn = 0; fn < 3; fn++) {
        int c = fn * 32 + (lane & 31);
        bf16x8 bfr = __builtin_bit_cast(bf16x8,
            *(const ushort8v*)(Bs + c * 128 + ((sl ^ (c & 7)) << 4)));
        acc[fn] = __builtin_amdgcn_mfma_f32_32x32x16_bf16(af, bfr, acc[fn], 0, 0, 0);
      }
    }
    __builtin_amdgcn_s_barrier();                // reads done before buf reuse
  }
#undef STAGE

  #pragma unroll
  for (int fn = 0; fn < 3; fn++) {
    int col = n * 96 + fn * 32 + (lane & 31);
    #pragma unroll
    for (int reg = 0; reg < 16; reg++) {
      int row = wid * 32 + (reg & 3) + ((reg >> 2) << 3) + ((lane >> 5) << 2);
      z[(row0 + row) * 672 + col] = acc[fn][reg];
    }
  }
}

// ---------- K1 fallback (round-3 version, f32 x direct) ----------
__launch_bounds__(GTHREADS, 4)
__global__ void gemm_fb(const float* __restrict__ x, const char* __restrict__ wbB,
                        float* __restrict__ z) {
  __shared__ __align__(16) char smem[BUF_BYTES];
  char* Bs = smem;
  char* As = smem + B_TILE_BYTES;

  const int tid = threadIdx.x;
  const int wid = tid >> 6, lane = tid & 63;
  const int bid = blockIdx.x;
  const int xcd = bid & 7, j = bid >> 3;
  const int panel = xcd * 32 + j / 7;
  const int n = j % 7;
  const size_t row0 = (size_t)panel * BM;

  f32x16 acc[3];
  #pragma unroll
  for (int f = 0; f < 3; f++)
    #pragma unroll
    for (int jj = 0; jj < 16; jj++) acc[f][jj] = 0.f;

  const int arow = tid >> 1, kh = tid & 1;
  const float* aptr = x + (row0 + arow) * 2048 + kh * 32;
  char* awbase = As + arow * 128;
  const int arow7 = arow & 7;
  const int arf = wid * 32 + (lane & 31);
  const char* afbase = As + arf * 128;
  const int arf7 = arf & 7;

  float4 av[8];
  #pragma unroll
  for (int jj = 0; jj < 8; jj++) av[jj] = ((const float4*)aptr)[jj];

  for (int t = 0; t < KITERS; t++) {
    __syncthreads();
    {
      const char* src = wbB + (size_t)t * WCHUNK + n * B_TILE_BYTES;
      #pragma unroll
      for (int rnd = 0; rnd < 3; rnd++) {
        int off = rnd * 4096 + tid * 16;
        __builtin_amdgcn_global_load_lds(
            (const __attribute__((address_space(1))) void*)(src + off),
            (__attribute__((address_space(3))) void*)(Bs + off), 16, 0, 0);
      }
    }
    #pragma unroll
    for (int s4 = 0; s4 < 4; s4++) {
      ushort8v v;
      v[0] = f2bf(av[s4 * 2].x);     v[1] = f2bf(av[s4 * 2].y);
      v[2] = f2bf(av[s4 * 2].z);     v[3] = f2bf(av[s4 * 2].w);
      v[4] = f2bf(av[s4 * 2 + 1].x); v[5] = f2bf(av[s4 * 2 + 1].y);
      v[6] = f2bf(av[s4 * 2 + 1].z); v[7] = f2bf(av[s4 * 2 + 1].w);
      int slot = (kh * 4 + s4) ^ arow7;
      *(ushort8v*)(awbase + slot * 16) = v;
    }
    __syncthreads();
    if (t + 1 < KITERS) {
      const float4* ap = (const float4*)(aptr + (t + 1) * 64);
      #pragma unroll
      for (int jj = 0; jj < 8; jj++) av[jj] = ap[jj];
    }
    #pragma unroll
    for (int k16 = 0; k16 < 4; k16++) {
      int sl = k16 * 2 + (lane >> 5);
      bf16x8 af = __builtin_bit_cast(bf16x8,
          *(const ushort8v*)(afbase + ((sl ^ arf7) << 4)));
      #pragma unroll
      for (int fn = 0; fn < 3; fn++) {
        int c = fn * 32 + (lane & 31);
        bf16x8 bfr = __builtin_bit_cast(bf16x8,
            *(const ushort8v*)(Bs + c * 128 + ((sl ^ (c & 7)) << 4)));
        acc[fn] = __builtin_amdgcn_mfma_f32_32x32x16_bf16(af, bfr, acc[fn], 0, 0, 0);
      }
    }
  }

  #pragma unroll
  for (int fn = 0; fn < 3; fn++) {
    int col = n * 96 + fn * 32 + (lane & 31);
    #pragma unroll
    for (int reg = 0; reg < 16; reg++) {
      int row = wid * 32 + (reg & 3) + ((reg >> 2) << 3) + ((lane >> 5) << 2);
      z[(row0 + row) * 672 + col] = acc[fn][reg];
    }
  }
}

// ---------- K2: Kuramoto dynamics + in-place scale of d_out ----------
#define ZSTR 164
#define DROWS 32
__launch_bounds__(256, 6)
__global__ void dyn_scale(float* __restrict__ z,
                          const float* __restrict__ pdt_p,
                          const float* __restrict__ ptg_p) {
  __shared__ float zdt[DROWS * ZSTR];
  __shared__ float Fbuf[2 * DROWS];
  const int tid = threadIdx.x;
  const int wid = tid >> 6, lane = tid & 63;
  const size_t row0 = (size_t)blockIdx.x * DROWS;

  for (int i = tid; i < DROWS * 40; i += 256) {
    int row = i / 40, c4 = i - row * 40;
    float4 v = *(const float4*)(z + (row0 + row) * 672 + c4 * 4);
    *(float4*)(&zdt[row * ZSTR + c4 * 4]) = v;
  }
  __syncthreads();

  const float pdt = fminf(fmaxf(pdt_p[0], 0.f), 1.f);
  const float ptg = fminf(fmaxf(ptg_p[0], 0.f), 1.f);

  for (int rr = 0; rr < 8; rr++) {
    int row = wid * 8 + rr;
    float pd  = (lane < 32) ? zdt[row * ZSTR + lane] : 0.f;
    float pt0 = zdt[row * ZSTR + 32 + lane];
    float pt1 = zdt[row * ZSTR + 96 + lane];
    float Ft = 1.f, Fg = 1.f;
    for (int s = 0; s < 10; s++) {
      float sd = __sinf(pd),  cd = __cosf(pd);
      float s0 = __sinf(pt0), c0 = __cosf(pt0);
      float s1 = __sinf(pt1), c1 = __cosf(pt1);
      float vCd = (lane < 32) ? cd : 0.f;
      float vSd = (lane < 32) ? sd : 0.f;
      float vCt = c0 + c1, vSt = s0 + s1;
      #pragma unroll
      for (int off = 32; off > 0; off >>= 1) {
        vCd += __shfl_xor(vCd, off);
        vSd += __shfl_xor(vSd, off);
        vCt += __shfl_xor(vCt, off);
        vSt += __shfl_xor(vSt, off);
      }
      float Cd = vCd * (1.f / 32.f),  Sd = vSd * (1.f / 32.f);
      float Ct = vCt * (1.f / 128.f), St = vSt * (1.f / 128.f);
      pd  += DTF * (TWO_PI_F * 2.f + KCOUP * (Sd * cd - Cd * sd));
      pt0 += DTF * (TWO_PI_F * 6.f + KCOUP * (St * c0 - Ct * s0));
      pt1 += DTF * (TWO_PI_F * 6.f + KCOUP * (St * c1 - Ct * s1));
      float rd = sqrtf(Cd * Cd + Sd * Sd) + EPSF;
      float rt = sqrtf(Ct * Ct + St * St) + EPSF;
      Ft *= (1.f + DTF * pdt * (Cd / rd));
      Fg *= (1.f + DTF * ptg * (Ct / rt));
    }
    if (lane == 0) { Fbuf[row] = Ft; Fbuf[DROWS + row] = Fg; }
  }
  __syncthreads();

  for (int i = tid; i < DROWS * 168; i += 256) {
    int row = i / 168, c4 = i - row * 168;
    float4* p = (float4*)(z + (row0 + row) * 672 + c4 * 4);
    float4 v = *p;
    float f = (c4 < 8) ? 1.f : (c4 < 40 ? Fbuf[row] : Fbuf[DROWS + row]);
    v.x = fmaxf(fmaxf(fabsf(v.x), EPSF) * f, EPSF);
    v.y = fmaxf(fmaxf(fabsf(v.y), EPSF) * f, EPSF);
    v.z = fmaxf(fmaxf(fabsf(v.z), EPSF) * f, EPSF);
    v.w = fmaxf(fmaxf(fabsf(v.w), EPSF) * f, EPSF);
    *p = v;
  }
}

extern "C" void kernel_launch(void* const* d_in, const int* in_sizes, int n_in,
                              void* d_out, int out_size, void* d_ws, size_t ws_size,
                              hipStream_t stream) {
  const float* x   = (const float*)d_in[0];
  const float* Wd  = (const float*)d_in[1];
  const float* Wt  = (const float*)d_in[2];
  const float* Wg  = (const float*)d_in[3];
  const float* pdt = (const float*)d_in[4];
  const float* ptg = (const float*)d_in[5];
  float* outp = (float*)d_out;
  char* wbB = (char*)d_ws;

  if (ws_size < WS_NEED_MIN) return;

  const int Brows = in_sizes[0] / 2048;           // 32768
  prep_w<<<(672 * 64 + 255) / 256, 256, 0, stream>>>(Wd, Wt, Wg, wbB);

  if (ws_size >= WS_NEED_FULL) {
    unsigned short* xb = (unsigned short*)(wbB + W_IMG_BYTES);
    const int n8 = Brows * 256;                   // elems/8
    prep_x<<<(n8 + 255) / 256, 256, 0, stream>>>(x, xb, n8);
    gemm<<<(Brows / BM) * NTILES, GTHREADS, 0, stream>>>(xb, wbB, outp);
  } else {
    gemm_fb<<<(Brows / BM) * NTILES, GTHREADS, 0, stream>>>(x, wbB, outp);
  }
  dyn_scale<<<Brows / DROWS, 256, 0, stream>>>(outp, pdt, ptg);
}

// Round 6
// 305.055 us; speedup vs baseline: 1.0239x; 1.0239x over previous
//
#include <hip/hip_runtime.h>
#include <stdint.h>

#define TWO_PI_F 6.28318530717958647692f
#define EPSF 1e-6f
#define DTF 0.01f
#define KCOUP 2.0f

// ---- GEMM geometry ----
#define BN 96
#define KITERS 32                 // 2048 / 64
#define NTILES 7                  // 672 / 96, exact
#define B_TILE_BYTES (BN * 128)   // 12288
#define WCHUNK (672 * 128)        // 86016 bytes per K-chunk of B image
#define W_IMG_BYTES ((size_t)KITERS * WCHUNK)          // 2,752,512
#define XB_BYTES ((size_t)32768 * 2048 * 2)            // 134,217,728
#define WS_NEED_FULL (W_IMG_BYTES + XB_BYTES)
#define WS_NEED_MIN  W_IMG_BYTES

typedef __attribute__((ext_vector_type(8)))  __bf16         bf16x8;
typedef __attribute__((ext_vector_type(8)))  unsigned short ushort8v;
typedef __attribute__((ext_vector_type(16))) float          f32x16;

__device__ __forceinline__ unsigned short f2bf(float f) {
  unsigned u = __builtin_bit_cast(unsigned, f);
  u = (u + 0x7FFFu + ((u >> 16) & 1u)) >> 16;   // RNE
  return (unsigned short)u;
}

// ---------- prep_w: W (f32) -> swizzled bf16 image [t][col][slot*16B] ----------
__global__ void prep_w(const float* __restrict__ Wd, const float* __restrict__ Wt,
                       const float* __restrict__ Wg, char* __restrict__ wbB) {
  int id = blockIdx.x * 256 + threadIdx.x;      // 672 * 64 total
  if (id >= 672 * 64) return;
  int col = id >> 6;
  int rem = id & 63, t = rem >> 1, h = rem & 1;
  const float* src = (col < 32)  ? Wd + (size_t)col * 2048
                   : (col < 160) ? Wt + (size_t)(col - 32) * 2048
                                 : Wg + (size_t)(col - 160) * 2048;
  src += t * 64 + h * 32;
  char* dst = wbB + ((size_t)t * 672 + col) * 128;
  #pragma unroll
  for (int s4 = 0; s4 < 4; s4++) {
    float4 a = ((const float4*)src)[s4 * 2];
    float4 b = ((const float4*)src)[s4 * 2 + 1];
    ushort8v v;
    v[0] = f2bf(a.x); v[1] = f2bf(a.y); v[2] = f2bf(a.z); v[3] = f2bf(a.w);
    v[4] = f2bf(b.x); v[5] = f2bf(b.y); v[6] = f2bf(b.z); v[7] = f2bf(b.w);
    int slot = (h * 4 + s4) ^ (col & 7);
    *(ushort8v*)(dst + slot * 16) = v;
  }
}

// ---------- prep_xf: x f32 -> bf16 in MFMA-fragment order [g][s][lane]x16B ----------
// block handles row-group g (32 rows) x k-quarter kq (512 k = 32 s-steps)
__global__ void prep_xf(const float* __restrict__ x, unsigned short* __restrict__ xbs) {
  __shared__ unsigned short lx[32][520];        // 33 KB, +8 pad vs bank collisions
  const int bid = blockIdx.x;
  const int g = bid >> 2, kq = bid & 3;
  const int tid = threadIdx.x;
  const int r = tid >> 3, q = tid & 7;
  const float* rowp = x + ((size_t)g * 32 + r) * 2048 + kq * 512;
  #pragma unroll
  for (int i = 0; i < 16; i++) {                // 64 floats per thread, coalesced
    float4 v = ((const float4*)rowp)[q + i * 8];
    int c = (q + i * 8) * 4;
    lx[r][c]     = f2bf(v.x); lx[r][c + 1] = f2bf(v.y);
    lx[r][c + 2] = f2bf(v.z); lx[r][c + 3] = f2bf(v.w);
  }
  __syncthreads();
  #pragma unroll
  for (int i = 0; i < 8; i++) {                 // 2048 frag-slots / 256 threads
    int idx = i * 256 + tid;
    int sloc = idx >> 6, lane = idx & 63;
    int srow = lane & 31, koff = sloc * 16 + (lane >> 5) * 8;
    ushort8v v;
    #pragma unroll
    for (int jj = 0; jj < 8; jj++) v[jj] = lx[srow][koff + jj];
    *(ushort8v*)(xbs + ((size_t)(g * 128 + kq * 32 + sloc) * 64 + lane) * 8) = v;
  }
}

// ---------- K1: BM=256, A direct-from-global frags, B LDS dbuf + counted vmcnt ----------
__launch_bounds__(256, 2)
__global__ void gemm_dr(const unsigned short* __restrict__ xbs,
                        const char* __restrict__ wbB, float* __restrict__ z) {
  __shared__ __align__(16) char smem[2 * B_TILE_BYTES];   // 24 KB

  const int tid = threadIdx.x;
  const int wid = tid >> 6, lane = tid & 63;

  // XCD-aware: each XCD owns exclusive row panels; 7 n-tiles of a panel adjacent
  const int ppx = (gridDim.x / NTILES) >> 3;    // panels per XCD
  const int bid = blockIdx.x;
  const int xcd = bid & 7, j = bid >> 3;
  const int panel = xcd * ppx + j / NTILES;
  const int n = j % NTILES;
  const size_t row0 = (size_t)panel * 256;
  const int g0 = panel * 8 + wid * 2;           // wave's first 32-row group

  f32x16 acc[6];                                // [rt*3+fn]
  #pragma unroll
  for (int f = 0; f < 6; f++)
    #pragma unroll
    for (int jj = 0; jj < 16; jj++) acc[f][jj] = 0.f;

  const char* bsrc0 = wbB + n * B_TILE_BYTES;
  const char* xbc = (const char*)xbs;
  const char* a0base = xbc + (size_t)g0 * 131072 + lane * 16;  // 128 s * 1024 B
  const char* a1base = a0base + 131072;

#define STAGE_B(buf, t)                                                       \
  { const char* bsrc = bsrc0 + (size_t)(t) * WCHUNK;                          \
    _Pragma("unroll")                                                         \
    for (int rnd = 0; rnd < 3; rnd++) {                                       \
      int off = rnd * 4096 + tid * 16;                                        \
      __builtin_amdgcn_global_load_lds(                                       \
        (const __attribute__((address_space(1))) void*)(bsrc + off),          \
        (__attribute__((address_space(3))) void*)(smem + (buf) * B_TILE_BYTES + off), \
        16, 0, 0); } }

#define LOADA(arr, t)                                                         \
  { _Pragma("unroll")                                                         \
    for (int s4 = 0; s4 < 4; s4++) {                                          \
      arr[s4]     = *(const ushort8v*)(a0base + ((t) * 4 + s4) * 1024);       \
      arr[4 + s4] = *(const ushort8v*)(a1base + ((t) * 4 + s4) * 1024); } }

#define COMPUTE(arr, buf)                                                     \
  { const char* Bs_ = smem + (buf) * B_TILE_BYTES;                            \
    _Pragma("unroll")                                                         \
    for (int s4 = 0; s4 < 4; s4++) {                                          \
      int sl = s4 * 2 + (lane >> 5);                                          \
      bf16x8 af0 = __builtin_bit_cast(bf16x8, arr[s4]);                       \
      bf16x8 af1 = __builtin_bit_cast(bf16x8, arr[4 + s4]);                   \
      _Pragma("unroll")                                                       \
      for (int fn = 0; fn < 3; fn++) {                                        \
        int c = fn * 32 + (lane & 31);                                        \
        bf16x8 bfr = __builtin_bit_cast(bf16x8,                               \
            *(const ushort8v*)(Bs_ + c * 128 + ((sl ^ (c & 7)) << 4)));       \
        acc[fn]     = __builtin_amdgcn_mfma_f32_32x32x16_bf16(af0, bfr, acc[fn],     0, 0, 0); \
        acc[3 + fn] = __builtin_amdgcn_mfma_f32_32x32x16_bf16(af1, bfr, acc[3 + fn], 0, 0, 0); } } }

  ushort8v aA[8], aB[8];
  LOADA(aA, 0);
  STAGE_B(0, 0);

  #pragma unroll
  for (int tt = 0; tt < KITERS; tt += 2) {
    // even iter tt: consume aA / buf0
    if (tt + 1 < KITERS) {
      STAGE_B(1, tt + 1); LOADA(aB, tt + 1);
      asm volatile("s_waitcnt vmcnt(11)" ::: "memory");  // tile tt's 3 gll + 8 A landed
    } else {
      asm volatile("s_waitcnt vmcnt(0)" ::: "memory");
    }
    __builtin_amdgcn_s_barrier();
    __builtin_amdgcn_sched_barrier(0);
    COMPUTE(aA, 0);
    __builtin_amdgcn_sched_barrier(0);
    __builtin_amdgcn_s_barrier();
    // odd iter tt+1: consume aB / buf1
    if (tt + 2 < KITERS) {
      STAGE_B(0, tt + 2); LOADA(aA, tt + 2);
      asm volatile("s_waitcnt vmcnt(11)" ::: "memory");
    } else {
      asm volatile("s_waitcnt vmcnt(0)" ::: "memory");
    }
    __builtin_amdgcn_s_barrier();
    __builtin_amdgcn_sched_barrier(0);
    COMPUTE(aB, 1);
    __builtin_amdgcn_sched_barrier(0);
    __builtin_amdgcn_s_barrier();
  }
#undef STAGE_B
#undef LOADA
#undef COMPUTE

  #pragma unroll
  for (int rt = 0; rt < 2; rt++)
    #pragma unroll
    for (int fn = 0; fn < 3; fn++) {
      int col = n * 96 + fn * 32 + (lane & 31);
      #pragma unroll
      for (int reg = 0; reg < 16; reg++) {
        int row = wid * 64 + rt * 32 + (reg & 3) + ((reg >> 2) << 3) + ((lane >> 5) << 2);
        z[(row0 + row) * 672 + col] = acc[rt * 3 + fn][reg];
      }
    }
}

// ---------- K1 fallback (round-3 style, f32 x direct) ----------
__launch_bounds__(256, 4)
__global__ void gemm_fb(const float* __restrict__ x, const char* __restrict__ wbB,
                        float* __restrict__ z) {
  __shared__ __align__(16) char smem[B_TILE_BYTES + 16384];
  char* Bs = smem;
  char* As = smem + B_TILE_BYTES;

  const int tid = threadIdx.x;
  const int wid = tid >> 6, lane = tid & 63;
  const int bid = blockIdx.x;
  const int xcd = bid & 7, j = bid >> 3;
  const int panel = xcd * 32 + j / NTILES;
  const int n = j % NTILES;
  const size_t row0 = (size_t)panel * 128;

  f32x16 acc[3];
  #pragma unroll
  for (int f = 0; f < 3; f++)
    #pragma unroll
    for (int jj = 0; jj < 16; jj++) acc[f][jj] = 0.f;

  const int arow = tid >> 1, kh = tid & 1;
  const float* aptr = x + (row0 + arow) * 2048 + kh * 32;
  char* awbase = As + arow * 128;
  const int arow7 = arow & 7;
  const int arf = wid * 32 + (lane & 31);
  const char* afbase = As + arf * 128;
  const int arf7 = arf & 7;

  float4 av[8];
  #pragma unroll
  for (int jj = 0; jj < 8; jj++) av[jj] = ((const float4*)aptr)[jj];

  for (int t = 0; t < KITERS; t++) {
    __syncthreads();
    {
      const char* src = wbB + (size_t)t * WCHUNK + n * B_TILE_BYTES;
      #pragma unroll
      for (int rnd = 0; rnd < 3; rnd++) {
        int off = rnd * 4096 + tid * 16;
        __builtin_amdgcn_global_load_lds(
            (const __attribute__((address_space(1))) void*)(src + off),
            (__attribute__((address_space(3))) void*)(Bs + off), 16, 0, 0);
      }
    }
    #pragma unroll
    for (int s4 = 0; s4 < 4; s4++) {
      ushort8v v;
      v[0] = f2bf(av[s4 * 2].x);     v[1] = f2bf(av[s4 * 2].y);
      v[2] = f2bf(av[s4 * 2].z);     v[3] = f2bf(av[s4 * 2].w);
      v[4] = f2bf(av[s4 * 2 + 1].x); v[5] = f2bf(av[s4 * 2 + 1].y);
      v[6] = f2bf(av[s4 * 2 + 1].z); v[7] = f2bf(av[s4 * 2 + 1].w);
      int slot = (kh * 4 + s4) ^ arow7;
      *(ushort8v*)(awbase + slot * 16) = v;
    }
    __syncthreads();
    if (t + 1 < KITERS) {
      const float4* ap = (const float4*)(aptr + (t + 1) * 64);
      #pragma unroll
      for (int jj = 0; jj < 8; jj++) av[jj] = ap[jj];
    }
    #pragma unroll
    for (int k16 = 0; k16 < 4; k16++) {
      int sl = k16 * 2 + (lane >> 5);
      bf16x8 af = __builtin_bit_cast(bf16x8,
          *(const ushort8v*)(afbase + ((sl ^ arf7) << 4)));
      #pragma unroll
      for (int fn = 0; fn < 3; fn++) {
        int c = fn * 32 + (lane & 31);
        bf16x8 bfr = __builtin_bit_cast(bf16x8,
            *(const ushort8v*)(Bs + c * 128 + ((sl ^ (c & 7)) << 4)));
        acc[fn] = __builtin_amdgcn_mfma_f32_32x32x16_bf16(af, bfr, acc[fn], 0, 0, 0);
      }
    }
  }

  #pragma unroll
  for (int fn = 0; fn < 3; fn++) {
    int col = n * 96 + fn * 32 + (lane & 31);
    #pragma unroll
    for (int reg = 0; reg < 16; reg++) {
      int row = wid * 32 + (reg & 3) + ((reg >> 2) << 3) + ((lane >> 5) << 2);
      z[(row0 + row) * 672 + col] = acc[fn][reg];
    }
  }
}

// ---------- K2: Kuramoto dynamics + in-place scale of d_out ----------
#define ZSTR 164
#define DROWS 32
__launch_bounds__(256, 6)
__global__ void dyn_scale(float* __restrict__ z,
                          const float* __restrict__ pdt_p,
                          const float* __restrict__ ptg_p) {
  __shared__ float zdt[DROWS * ZSTR];
  __shared__ float Fbuf[2 * DROWS];
  const int tid = threadIdx.x;
  const int wid = tid >> 6, lane = tid & 63;
  const size_t row0 = (size_t)blockIdx.x * DROWS;

  for (int i = tid; i < DROWS * 40; i += 256) {
    int row = i / 40, c4 = i - row * 40;
    float4 v = *(const float4*)(z + (row0 + row) * 672 + c4 * 4);
    *(float4*)(&zdt[row * ZSTR + c4 * 4]) = v;
  }
  __syncthreads();

  const float pdt = fminf(fmaxf(pdt_p[0], 0.f), 1.f);
  const float ptg = fminf(fmaxf(ptg_p[0], 0.f), 1.f);

  for (int rr = 0; rr < 8; rr++) {
    int row = wid * 8 + rr;
    float pd  = (lane < 32) ? zdt[row * ZSTR + lane] : 0.f;
    float pt0 = zdt[row * ZSTR + 32 + lane];
    float pt1 = zdt[row * ZSTR + 96 + lane];
    float Ft = 1.f, Fg = 1.f;
    for (int s = 0; s < 10; s++) {
      float sd = __sinf(pd),  cd = __cosf(pd);
      float s0 = __sinf(pt0), c0 = __cosf(pt0);
      float s1 = __sinf(pt1), c1 = __cosf(pt1);
      float vCd = (lane < 32) ? cd : 0.f;
      float vSd = (lane < 32) ? sd : 0.f;
      float vCt = c0 + c1, vSt = s0 + s1;
      #pragma unroll
      for (int off = 32; off > 0; off >>= 1) {
        vCd += __shfl_xor(vCd, off);
        vSd += __shfl_xor(vSd, off);
        vCt += __shfl_xor(vCt, off);
        vSt += __shfl_xor(vSt, off);
      }
      float Cd = vCd * (1.f / 32.f),  Sd = vSd * (1.f / 32.f);
      float Ct = vCt * (1.f / 128.f), St = vSt * (1.f / 128.f);
      pd  += DTF * (TWO_PI_F * 2.f + KCOUP * (Sd * cd - Cd * sd));
      pt0 += DTF * (TWO_PI_F * 6.f + KCOUP * (St * c0 - Ct * s0));
      pt1 += DTF * (TWO_PI_F * 6.f + KCOUP * (St * c1 - Ct * s1));
      float rd = sqrtf(Cd * Cd + Sd * Sd) + EPSF;
      float rt = sqrtf(Ct * Ct + St * St) + EPSF;
      Ft *= (1.f + DTF * pdt * (Cd / rd));
      Fg *= (1.f + DTF * ptg * (Ct / rt));
    }
    if (lane == 0) { Fbuf[row] = Ft; Fbuf[DROWS + row] = Fg; }
  }
  __syncthreads();

  for (int i = tid; i < DROWS * 168; i += 256) {
    int row = i / 168, c4 = i - row * 168;
    float4* p = (float4*)(z + (row0 + row) * 672 + c4 * 4);
    float4 v = *p;
    float f = (c4 < 8) ? 1.f : (c4 < 40 ? Fbuf[row] : Fbuf[DROWS + row]);
    v.x = fmaxf(fmaxf(fabsf(v.x), EPSF) * f, EPSF);
    v.y = fmaxf(fmaxf(fabsf(v.y), EPSF) * f, EPSF);
    v.z = fmaxf(fmaxf(fabsf(v.z), EPSF) * f, EPSF);
    v.w = fmaxf(fmaxf(fabsf(v.w), EPSF) * f, EPSF);
    *p = v;
  }
}

extern "C" void kernel_launch(void* const* d_in, const int* in_sizes, int n_in,
                              void* d_out, int out_size, void* d_ws, size_t ws_size,
                              hipStream_t stream) {
  const float* x   = (const float*)d_in[0];
  const float* Wd  = (const float*)d_in[1];
  const float* Wt  = (const float*)d_in[2];
  const float* Wg  = (const float*)d_in[3];
  const float* pdt = (const float*)d_in[4];
  const float* ptg = (const float*)d_in[5];
  float* outp = (float*)d_out;
  char* wbB = (char*)d_ws;

  if (ws_size < WS_NEED_MIN) return;

  const int Brows = in_sizes[0] / 2048;           // 32768
  prep_w<<<(672 * 64 + 255) / 256, 256, 0, stream>>>(Wd, Wt, Wg, wbB);

  if (ws_size >= WS_NEED_FULL && (Brows % 2048) == 0) {
    unsigned short* xbs = (unsigned short*)(wbB + W_IMG_BYTES);
    prep_xf<<<(Brows / 32) * 4, 256, 0, stream>>>(x, xbs);
    gemm_dr<<<(Brows / 256) * NTILES, 256, 0, stream>>>(xbs, wbB, outp);
  } else {
    gemm_fb<<<(Brows / 128) * NTILES, 256, 0, stream>>>(x, wbB, outp);
  }
  dyn_scale<<<Brows / DROWS, 256, 0, stream>>>(outp, pdt, ptg);
}